// Round 7
// baseline (801.267 us; speedup 1.0000x reference)
//
#include <hip/hip_runtime.h>
#include <hip/hip_fp16.h>

#define Bb 4
#define Nn 20000
#define Ee 320000
#define CIN 32
#define COUT 32
#define Kk 16
#define Mm 2
#define NB 157      /* buckets per slice, 128 nodes each (last = 32) */
#define QN 128      /* nodes per bucket */
#define WW 64       /* binning blocks per slice; chunk = Ee/WW = 5000 edges */
#define CHK 5000

typedef __attribute__((ext_vector_type(8))) _Float16 half8;
typedef __attribute__((ext_vector_type(4))) float f32x4;

// ---------------- kernel 1: prep: transpose f -> fT (fp16); pack pb (fp16), pn
__global__ __launch_bounds__(256) void prep_fused(
    const float* __restrict__ f,
    const float4* __restrict__ bc4,
    const float4* __restrict__ bs4,
    const float* __restrict__ nodes,
    const float* __restrict__ nrm,
    __half* __restrict__ fT,          // [b][n][32] fp16
    __half* __restrict__ pb,          // [(b*2+m)][n][32] fp16: [bc 0..15 | bs 0..15]
    float4* __restrict__ pn) {
    __shared__ float ldsT[32 * 33];
    __shared__ float ldc[32 * 33];
    __shared__ float ldss[32 * 33];
    const int t   = threadIdx.x;
    const int blk = blockIdx.x;            // 2500 blocks
    const int b   = blk / 625;
    const int n0  = (blk % 625) * 32;
    {
        int lane = t & 31, grp = t >> 5;
        #pragma unroll
        for (int r = 0; r < 4; ++r)
            ldsT[(grp + r * 8) * 33 + lane] = f[(b * CIN + grp + r * 8) * Nn + n0 + lane];
        __syncthreads();
        int nl = t >> 3, c4 = (t & 7) * 4;
        union { short4 s4; __half h[4]; } u;
        #pragma unroll
        for (int j = 0; j < 4; ++j)
            u.h[j] = __float2half(ldsT[(c4 + j) * 33 + nl]);
        *(short4*)(fT + ((size_t)(b * Nn) + n0 + nl) * CIN + c4) = u.s4;
    }
    {
        int nl = t >> 3, j4 = t & 7;
        float4 vc = bc4[(b * Nn + n0 + nl) * 8 + j4];
        float4 vs = bs4[(b * Nn + n0 + nl) * 8 + j4];
        float* pc = ldc + nl * 33 + 4 * j4;
        pc[0] = vc.x; pc[1] = vc.y; pc[2] = vc.z; pc[3] = vc.w;
        float* ps = ldss + nl * 33 + 4 * j4;
        ps[0] = vs.x; ps[1] = vs.y; ps[2] = vs.z; ps[3] = vs.w;
        __syncthreads();
        int m = (t >> 2) & 1, chunk = t & 3;
        const float* src = (chunk < 2 ? ldc : ldss) + nl * 33;
        int k0 = (chunk & 1) * 8;
        union { float4 v; __half h[8]; } o;
        #pragma unroll
        for (int j = 0; j < 8; ++j)
            o.h[j] = __float2half(src[2 * (k0 + j) + m]);
        ((float4*)pb)[(((size_t)(b * 2 + m)) * Nn + n0 + nl) * 4 + chunk] = o.v;
    }
    const int t0 = blk * 256 + t, S = 2500 * 256;
    for (int i = t0; i < Bb * Nn; i += S) {
        float2 nd = ((const float2*)nodes)[i];
        float2 nv = ((const float2*)nrm)[i];
        pn[i] = make_float4(nd.x, nd.y, nv.x, nv.y);
    }
}

// ---------------- kernel 2: per-(slice,bucket,block) histogram (plain stores, exclusive)
__global__ __launch_bounds__(256) void hist_kernel(
    const int2* __restrict__ tg,       // de viewed as int2: element 2i = {t_m0, t_m1}
    unsigned* __restrict__ cnt) {      // [8][NB][WW]
    __shared__ unsigned h0[NB], h1[NB];
    const int t = threadIdx.x;
    const int b = blockIdx.x >> 6;     // 4 b x 64 w
    const int w = blockIdx.x & 63;
    for (int i = t; i < NB; i += 256) { h0[i] = 0u; h1[i] = 0u; }
    __syncthreads();
    for (int it = 0; it < 20; ++it) {
        int el = it * 256 + t;
        if (el < CHK) {
            int2 tt = tg[((size_t)b * Ee + w * CHK + el) * 2];
            atomicAdd(&h0[tt.x >> 7], 1u);
            atomicAdd(&h1[tt.y >> 7], 1u);
        }
    }
    __syncthreads();
    for (int j = t; j < NB; j += 256) {
        cnt[(((b * 2 + 0) * NB) + j) * WW + w] = h0[j];
        cnt[(((b * 2 + 1) * NB) + j) * WW + w] = h1[j];
    }
}

// ---------------- kernel 3: per-slice exclusive scan of cnt (NB*WW=10048) + bucket starts
__global__ __launch_bounds__(256) void scan_kernel(
    unsigned* __restrict__ cnt, unsigned* __restrict__ bstart) {
    __shared__ unsigned part[256];
    const int s = blockIdx.x;          // 8 slices
    unsigned* cc = cnt + (size_t)s * NB * WW;
    const int N  = NB * WW;            // 10048
    const int t  = threadIdx.x;
    const int i0 = t * 40;
    const int i1 = (i0 + 40 < N) ? i0 + 40 : N;
    unsigned sum = 0;
    for (int i = i0; i < i1; ++i) sum += cc[i];
    part[t] = sum;
    __syncthreads();
    for (int d = 1; d < 256; d <<= 1) {
        unsigned v = (t >= d) ? part[t - d] : 0u;
        __syncthreads();
        part[t] += v;
        __syncthreads();
    }
    unsigned run = t ? part[t - 1] : 0u;
    for (int i = i0; i < i1; ++i) { unsigned v = cc[i]; cc[i] = run; run += v; }
    __syncthreads();
    for (int j = t; j < NB; j += 256) bstart[s * (NB + 1) + j] = cc[j * WW];
    if (t == 0) bstart[s * (NB + 1) + NB] = Ee;
}

// ---------------- kernel 4: geometry + batch-counting-sort scatter (coalesced record writes)
// record: x = tgt | (src<<15), y = bits(scale)
__global__ __launch_bounds__(256) void scatter_kernel(
    const int4* __restrict__ de4,
    const float4* __restrict__ pn,
    const float2* __restrict__ nwt2,
    const unsigned* __restrict__ cnt,  // per-(s,j,w) exclusive offsets (slice-local)
    uint2* __restrict__ srec) {
    __shared__ uint2 recL[2048];
    __shared__ unsigned short bktL[2048];
    __shared__ unsigned gcur[NB];
    __shared__ unsigned gbA[NB];
    __shared__ unsigned hist[NB + 1];
    __shared__ unsigned bsA[NB + 1];
    __shared__ unsigned scanp[256];
    const int t = threadIdx.x;
    const int s = blockIdx.x & 7;      // slice (XCD-spread)
    const int w = blockIdx.x >> 3;     // 0..63
    const int b = s >> 1, m = s & 1;
    const float4* pnb = pn + b * Nn;
    uint2* srs = srec + (size_t)s * Ee;

    for (int j = t; j < NB; j += 256) gcur[j] = cnt[((size_t)s * NB + j) * WW + w];
    __syncthreads();

    for (int batch = 0; batch < 3; ++batch) {
        const int bb = batch * 2048;
        if (t < NB + 1) hist[t] = 0u;
        __syncthreads();
        uint2 myrec[8];
        int   myj[8];
        #pragma unroll
        for (int k = 0; k < 8; ++k) {
            int el = bb + k * 256 + t;
            int j = NB;
            uint2 rec = make_uint2(0u, 0u);
            if (el < CHK) {
                int4 d4 = de4[(size_t)b * Ee + w * CHK + el];
                float2 nw = nwt2[(size_t)b * Ee + w * CHK + el];
                int tn = m ? d4.y : d4.x;
                int sn = m ? d4.w : d4.z;
                float4 qt = pnb[tn];
                float4 qs = pnb[sn];
                float dx = qt.x - qs.x, dy = qt.y - qs.y;
                float r2 = dx * dx + dy * dy + 1e-6f;
                float sc = (m ? nw.y : nw.x) * (dx * qs.z + dy * qs.w) / r2;
                rec = make_uint2((unsigned)tn | ((unsigned)sn << 15), __float_as_uint(sc));
                j = tn >> 7;
            }
            myrec[k] = rec; myj[k] = j;
            atomicAdd(&hist[j], 1u);
        }
        __syncthreads();
        // block exclusive scan of hist[0..NB]
        unsigned x = (t < NB + 1) ? hist[t] : 0u;
        scanp[t] = x;
        __syncthreads();
        for (int d = 1; d < 256; d <<= 1) {
            unsigned v = (t >= d) ? scanp[t - d] : 0u;
            __syncthreads();
            scanp[t] += v;
            __syncthreads();
        }
        if (t < NB + 1) bsA[t] = scanp[t] - x;
        __syncthreads();
        if (t < NB) { gbA[t] = gcur[t]; gcur[t] += hist[t]; }
        __syncthreads();
        if (t < NB + 1) hist[t] = bsA[t];   // reuse as placement cursor
        __syncthreads();
        #pragma unroll
        for (int k = 0; k < 8; ++k) {
            unsigned slot = atomicAdd(&hist[myj[k]], 1u);
            recL[slot] = myrec[k];
            bktL[slot] = (unsigned short)myj[k];
        }
        __syncthreads();
        const unsigned validN = bsA[NB];
        for (unsigned i = t; i < validN; i += 256) {
            int jj = bktL[i];
            srs[gbA[jj] + (i - bsA[jj])] = recL[i];
        }
        __syncthreads();
    }
}

// ---------------- kernel 5: bucket accumulate: records -> MFMA matvec -> LDS fp32 acc
//                  -> coalesced fp16 stores. ZERO global atomics.
__global__ __launch_bounds__(256, 4) void accum_kernel(
    const float4* __restrict__ pbh4,   // pb fp16 viewed as float4 (4 chunks/row)
    const __half* __restrict__ fTh,
    const uint2* __restrict__ srec,
    const unsigned* __restrict__ bstart,
    const float* __restrict__ wc,
    const float* __restrict__ wsp,
    const float* __restrict__ w0,
    __half* __restrict__ f_out) {      // [b][n][32] fp16
    __shared__ __align__(16) __half spb[4][16 * 64];   // 8 KB
    __shared__ float acc[QN * 33];                     // 16.9 KB
    const int t  = threadIdx.x;
    const int wv = t >> 6;
    const int l  = t & 63;
    const int c  = l & 15;
    const int q  = l >> 4;
    const int mode = q >> 1;
    const unsigned smask2 = mode ? 0x80008000u : 0u;
    const int b    = blockIdx.x / NB;
    const int j    = blockIdx.x % NB;
    const int base = j << 7;
    const int fbase = b * Nn;

    for (int i = t; i < QN * 33; i += 256) acc[i] = 0.f;
    __syncthreads();

    __half* myld = spb[wv];
    const int il = l >> 2, jj4 = l & 3;
    // LDS addresses: phys chunk = logical ^ (row & 7) -> conflict-free b128
    float4* wT = (float4*)(myld + il * 64 + 8 * (jj4 ^ (il & 7)));
    float4* wS = (float4*)(myld + il * 64 + 8 * ((4 | jj4) ^ (il & 7)));
    const int cs = c & 7;
    const float4* rBC = (const float4*)(myld + c * 64 + 8 * ((q & 1) ^ cs));
    const float4* rBS = (const float4*)(myld + c * 64 + 8 * ((2 | (q & 1)) ^ cs));
    const float4* rXX = (const float4*)(myld + c * 64 + 8 * ((4 | q) ^ cs));
    const float4* rYY = (const float4*)(myld + c * 64 + 8 * ((4 | (q ^ 2)) ^ cs));

    for (int m = 0; m < 2; ++m) {
        // loop-invariant B fragments (weights, fp16) for this m
        half8 bf0, bf1;
        #pragma unroll
        for (int jk = 0; jk < 8; ++jk) {
            int k = q * 8 + jk;
            float w0v, w1v;
            if (k < 16) {
                w0v = 2.0f * wc[(c * Kk + k) * Mm + m];
                w1v = 2.0f * wc[((c + 16) * Kk + k) * Mm + m];
            } else {
                w0v = 2.0f * wsp[(c * Kk + (k - 16)) * Mm + m];
                w1v = 2.0f * wsp[((c + 16) * Kk + (k - 16)) * Mm + m];
            }
            bf0[jk] = (_Float16)w0v;
            bf1[jk] = (_Float16)w1v;
        }
        const float acc00 = w0[c * Mm + m] + 1.0f;
        const float acc01 = w0[(c + 16) * Mm + m] + 1.0f;
        const int s = b * 2 + m;
        const int pbbase = s * Nn;
        const unsigned rs = bstart[s * (NB + 1) + j];
        const unsigned re = bstart[s * (NB + 1) + j + 1];
        const unsigned cntr = re - rs;
        if (cntr == 0) continue;
        const int ngroups = (int)((cntr + 255u) >> 8);
        const uint2* rb = srec + (size_t)s * Ee;
        const unsigned dummyx = (unsigned)base | ((unsigned)base << 15);

        unsigned idx0 = rs + wv * 64 + l;
        uint2 rc = (idx0 < re) ? rb[idx0] : make_uint2(dummyx, 0u);
        float scf = __uint_as_float(rc.y);
        float4 g0, g2;
        float fa[4], fb[4];
        {   // prologue prefetch for (g=0, tau=0)
            unsigned px = (unsigned)__shfl((int)rc.x, il);
            int tn = px & 32767, sn = (px >> 15) & 32767;
            g0 = pbh4[(size_t)(pbbase + tn) * 4 + jj4];
            g2 = pbh4[(size_t)(pbbase + sn) * 4 + jj4];
            #pragma unroll
            for (int r = 0; r < 4; ++r) {
                unsigned pf = (unsigned)__shfl((int)rc.x, 4 * q + r);
                int sr = (pf >> 15) & 32767;
                fa[r] = __half2float(fTh[(size_t)(fbase + sr) * CIN + c]);
                fb[r] = __half2float(fTh[(size_t)(fbase + sr) * CIN + c + 16]);
            }
        }
        uint2 rn;
        for (int g = 0; g < ngroups; ++g) {
            const bool lastg = (g == ngroups - 1);
            if (!lastg) {
                unsigned idn = rs + (unsigned)(g + 1) * 256 + wv * 64 + l;
                rn = (idn < re) ? rb[idn] : make_uint2(dummyx, 0u);
            }
            #pragma unroll
            for (int tau = 0; tau < 4; ++tau) {
                // 1. commit prefetched pb rows to LDS (swizzled)
                *wT = g0;
                *wS = g2;
                // 2. A-frag + MFMA (verified R1/R6 math)
                union { float4 v; unsigned u[4]; } ubc, ubs, uxx, uyy;
                ubc.v = *rBC; ubs.v = *rBS; uxx.v = *rXX; uyy.v = *rYY;
                union { half8 h8; unsigned u[4]; } af;
                #pragma unroll
                for (int jp = 0; jp < 4; ++jp) {
                    unsigned bsbits = ubs.u[jp] ^ smask2;
                    __half2 hb = *(__half2*)&ubc.u[jp];
                    __half2 hs = *(__half2*)&bsbits;
                    __half2 hx = *(__half2*)&uxx.u[jp];
                    __half2 hy = *(__half2*)&uyy.u[jp];
                    __half2 v  = __hfma2(hb, hx, __hmul2(hs, hy));
                    af.u[jp] = *(unsigned*)&v;
                }
                f32x4 zero = {0.f, 0.f, 0.f, 0.f};
                f32x4 d0 = __builtin_amdgcn_mfma_f32_16x16x32_f16(af.h8, bf0, zero, 0, 0, 0);
                f32x4 d1 = __builtin_amdgcn_mfma_f32_16x16x32_f16(af.h8, bf1, zero, 0, 0, 0);
                // 3. epilogue: ds_add into bucket-local fp32 accumulator
                #pragma unroll
                for (int r = 0; r < 4; ++r) {
                    int srcl = tau * 16 + 4 * q + r;
                    float sc = __shfl(scf, srcl);
                    int tn  = ((unsigned)__shfl((int)rc.x, srcl)) & 32767;
                    float v0 = (acc00 + d0[r]) * fa[r] * sc;
                    float v1 = (acc01 + d1[r]) * fb[r] * sc;
                    int lt = tn - base;
                    atomicAdd(&acc[lt * 33 + c], v0);
                    atomicAdd(&acc[lt * 33 + c + 16], v1);
                }
                // 4. prefetch next tau (or next group's tau 0)
                if (tau < 3 || !lastg) {
                    const int ntau = (tau == 3) ? 0 : tau + 1;
                    const unsigned bx = (tau == 3) ? rn.x : rc.x;
                    int srcA = ntau * 16 + il;
                    unsigned px = (unsigned)__shfl((int)bx, srcA);
                    int tn = px & 32767, sn = (px >> 15) & 32767;
                    g0 = pbh4[(size_t)(pbbase + tn) * 4 + jj4];
                    g2 = pbh4[(size_t)(pbbase + sn) * 4 + jj4];
                    #pragma unroll
                    for (int r = 0; r < 4; ++r) {
                        unsigned pf = (unsigned)__shfl((int)bx, ntau * 16 + 4 * q + r);
                        int sr = (pf >> 15) & 32767;
                        fa[r] = __half2float(fTh[(size_t)(fbase + sr) * CIN + c]);
                        fb[r] = __half2float(fTh[(size_t)(fbase + sr) * CIN + c + 16]);
                    }
                }
            }
            if (!lastg) { rc = rn; scf = __uint_as_float(rc.y); }
        }
    }
    __syncthreads();
    // coalesced fp16 write-out: 2 threads per row, 16 channels each
    {
        int row = t >> 1, h16 = t & 1;
        int n = base + row;
        if (n < Nn) {
            const float* ar = acc + row * 33 + h16 * 16;
            union { float4 v; __half2 h[4]; } o0, o1;
            #pragma unroll
            for (int i2 = 0; i2 < 4; ++i2) o0.h[i2] = __floats2half2_rn(ar[2 * i2], ar[2 * i2 + 1]);
            #pragma unroll
            for (int i2 = 0; i2 < 4; ++i2) o1.h[i2] = __floats2half2_rn(ar[8 + 2 * i2], ar[9 + 2 * i2]);
            float4* dst = (float4*)(f_out + ((size_t)fbase + n) * CIN + h16 * 16);
            dst[0] = o0.v;
            dst[1] = o1.v;
        }
    }
}

// ---------------- kernel 6: out[b,o,n] = bias[o] + sum_i wk[o,i] * f_out[b,n,i]
__global__ __launch_bounds__(256) void out_kernel(
    const float4* __restrict__ f_out4,    // fp16 data viewed as float4 (8 halves)
    const float* __restrict__ wk,
    const float* __restrict__ bias,
    float* __restrict__ out) {
    __shared__ float lwk[1024];
    __shared__ float lf[64 * 33];
    int blk  = blockIdx.x;
    int b    = blk / 313;
    int tile = blk % 313;
    int n0   = tile * 64;
    int t    = threadIdx.x;
    #pragma unroll
    for (int r = 0; r < 4; ++r) lwk[r * 256 + t] = wk[r * 256 + t];
    {
        int nl = t >> 2, i8 = t & 3;
        int n  = n0 + nl;
        union { float4 v; __half2 h[4]; } u;
        u.v = (n < Nn) ? f_out4[((size_t)b * Nn + n) * 4 + i8]
                       : make_float4(0, 0, 0, 0);
        float* p = lf + nl * 33 + i8 * 8;
        #pragma unroll
        for (int j = 0; j < 4; ++j) {
            float2 fj = __half22float2(u.h[j]);
            p[2 * j]     = fj.x;
            p[2 * j + 1] = fj.y;
        }
    }
    __syncthreads();
    int nl = t & 63;
    int og = t >> 6;
    int n  = n0 + nl;
    if (n < Nn) {
        #pragma unroll
        for (int r = 0; r < 8; ++r) {
            int o = r * 4 + og;
            float acc = bias[o];
            #pragma unroll
            for (int i = 0; i < 32; ++i) acc += lwk[o * 32 + i] * lf[nl * 33 + i];
            out[(b * COUT + o) * Nn + n] = acc;
        }
    }
}

extern "C" void kernel_launch(void* const* d_in, const int* in_sizes, int n_in,
                              void* d_out, int out_size, void* d_ws, size_t ws_size,
                              hipStream_t stream) {
    const float* f       = (const float*)d_in[0];
    const float* bases_c = (const float*)d_in[1];
    const float* bases_s = (const float*)d_in[2];
    const float* nodes   = (const float*)d_in[4];
    const float* nrm     = (const float*)d_in[5];
    const int*   de      = (const int*)d_in[6];
    const float* nwt     = (const float*)d_in[7];
    const float* wc      = (const float*)d_in[8];
    const float* wsp     = (const float*)d_in[9];
    const float* w0      = (const float*)d_in[10];
    const float* wk      = (const float*)d_in[11];
    const float* bias    = (const float*)d_in[12];
    float* out = (float*)d_out;

    __half*   fT     = (__half*)d_ws;                          // 5.12 MB
    __half*   pb     = fT + 2560000;                           // 10.24 MB
    float4*   pn     = (float4*)(pb + 5120000);                // 1.28 MB
    __half*   f_out  = (__half*)(pn + 80000);                  // 5.12 MB
    uint2*    srec   = (uint2*)(f_out + 2560000);              // 20.48 MB
    unsigned* cnt    = (unsigned*)(srec + 2560000);            // 321.5 KB
    unsigned* bstart = cnt + 8 * NB * WW;                      // 5.1 KB (ends 42.57 MB)

    prep_fused<<<2500, 256, 0, stream>>>(f, (const float4*)bases_c,
                                         (const float4*)bases_s, nodes, nrm,
                                         fT, pb, pn);
    hist_kernel<<<256, 256, 0, stream>>>((const int2*)de, cnt);
    scan_kernel<<<8, 256, 0, stream>>>(cnt, bstart);
    scatter_kernel<<<512, 256, 0, stream>>>((const int4*)de, pn,
                                            (const float2*)nwt, cnt, srec);
    accum_kernel<<<Bb * NB, 256, 0, stream>>>((const float4*)pb, fT, srec, bstart,
                                              wc, wsp, w0, f_out);
    out_kernel<<<Bb * 313, 256, 0, stream>>>((const float4*)f_out, wk, bias, out);
}

// Round 9
// 732.624 us; speedup vs baseline: 1.0937x; 1.0937x over previous
//
#include <hip/hip_runtime.h>
#include <hip/hip_fp16.h>

#define Bb 4
#define Nn 20000
#define Ee 320000
#define CIN 32
#define COUT 32
#define Kk 16
#define Mm 2
#define NB 157      /* buckets per slice, 128 nodes each (last = 32) */
#define QN 128      /* nodes per bucket */
#define WW 32       /* binning blocks per slice; chunk = Ee/WW = 10000 edges */
#define CHK 10000

typedef __attribute__((ext_vector_type(8))) _Float16 half8;
typedef __attribute__((ext_vector_type(4))) float f32x4;
typedef __attribute__((ext_vector_type(2))) unsigned u32x2;

// ---------------- kernel 1: prep: transpose f -> fT (fp16); pack pb (fp16), pn; zero f_out
__global__ __launch_bounds__(256) void prep_fused(
    const float* __restrict__ f,
    const float4* __restrict__ bc4,
    const float4* __restrict__ bs4,
    const float* __restrict__ nodes,
    const float* __restrict__ nrm,
    __half* __restrict__ fT,          // [b][n][32] fp16
    float4* __restrict__ f_outz,      // fp16 accumulator viewed as float4 for zeroing
    __half* __restrict__ pb,          // [(b*2+m)][n][32] fp16: [bc 0..15 | bs 0..15]
    float4* __restrict__ pn) {
    __shared__ float ldsT[32 * 33];
    __shared__ float ldc[32 * 33];
    __shared__ float ldss[32 * 33];
    const int t   = threadIdx.x;
    const int blk = blockIdx.x;            // 2500 blocks
    const int b   = blk / 625;
    const int n0  = (blk % 625) * 32;
    {
        int lane = t & 31, grp = t >> 5;
        #pragma unroll
        for (int r = 0; r < 4; ++r)
            ldsT[(grp + r * 8) * 33 + lane] = f[(b * CIN + grp + r * 8) * Nn + n0 + lane];
        __syncthreads();
        int nl = t >> 3, c4 = (t & 7) * 4;
        union { short4 s4; __half h[4]; } u;
        #pragma unroll
        for (int j = 0; j < 4; ++j)
            u.h[j] = __float2half(ldsT[(c4 + j) * 33 + nl]);
        *(short4*)(fT + ((size_t)(b * Nn) + n0 + nl) * CIN + c4) = u.s4;
    }
    {
        int nl = t >> 3, j4 = t & 7;
        float4 vc = bc4[(b * Nn + n0 + nl) * 8 + j4];
        float4 vs = bs4[(b * Nn + n0 + nl) * 8 + j4];
        float* pc = ldc + nl * 33 + 4 * j4;
        pc[0] = vc.x; pc[1] = vc.y; pc[2] = vc.z; pc[3] = vc.w;
        float* ps = ldss + nl * 33 + 4 * j4;
        ps[0] = vs.x; ps[1] = vs.y; ps[2] = vs.z; ps[3] = vs.w;
        __syncthreads();
        int m = (t >> 2) & 1, chunk = t & 3;
        const float* src = (chunk < 2 ? ldc : ldss) + nl * 33;
        int k0 = (chunk & 1) * 8;
        union { float4 v; __half h[8]; } o;
        #pragma unroll
        for (int j = 0; j < 8; ++j)
            o.h[j] = __float2half(src[2 * (k0 + j) + m]);
        ((float4*)pb)[(((size_t)(b * 2 + m)) * Nn + n0 + nl) * 4 + chunk] = o.v;
    }
    const int t0 = blk * 256 + t, S = 2500 * 256;
    // f_out is Bb*Nn*32 halves = 5.12 MB = 320000 float4 (atomic-merged by accum)
    for (int i = t0; i < 320000; i += S) f_outz[i] = make_float4(0, 0, 0, 0);
    for (int i = t0; i < Bb * Nn; i += S) {
        float2 nd = ((const float2*)nodes)[i];
        float2 nv = ((const float2*)nrm)[i];
        pn[i] = make_float4(nd.x, nd.y, nv.x, nv.y);
    }
}

// ---------------- kernel 2: per-(slice,bucket,block) histogram (plain stores, exclusive)
__global__ __launch_bounds__(256) void hist_kernel(
    const int2* __restrict__ tg,       // de viewed as int2: element 2i = {t_m0, t_m1}
    unsigned* __restrict__ cnt) {      // [8][NB][WW]
    __shared__ unsigned h0[NB], h1[NB];
    const int t = threadIdx.x;
    const int b = blockIdx.x >> 5;     // 4 b x 32 w
    const int w = blockIdx.x & 31;
    for (int i = t; i < NB; i += 256) { h0[i] = 0u; h1[i] = 0u; }
    __syncthreads();
    for (int it = 0; it < 40; ++it) {
        int el = it * 256 + t;
        if (el < CHK) {
            int2 tt = tg[((size_t)b * Ee + w * CHK + el) * 2];
            atomicAdd(&h0[tt.x >> 7], 1u);
            atomicAdd(&h1[tt.y >> 7], 1u);
        }
    }
    __syncthreads();
    for (int j = t; j < NB; j += 256) {
        cnt[(((b * 2 + 0) * NB) + j) * WW + w] = h0[j];
        cnt[(((b * 2 + 1) * NB) + j) * WW + w] = h1[j];
    }
}

// ---------------- kernel 3: per-slice exclusive scan of cnt (NB*WW=5024) + bucket starts
__global__ __launch_bounds__(256) void scan_kernel(
    unsigned* __restrict__ cnt, unsigned* __restrict__ bstart) {
    __shared__ unsigned part[256];
    const int s = blockIdx.x;          // 8 slices
    unsigned* cc = cnt + (size_t)s * NB * WW;
    const int N  = NB * WW;            // 5024
    const int t  = threadIdx.x;
    const int i0 = t * 20;
    const int i1 = (i0 + 20 < N) ? i0 + 20 : N;
    unsigned sum = 0;
    for (int i = i0; i < i1; ++i) sum += cc[i];
    part[t] = sum;
    __syncthreads();
    for (int d = 1; d < 256; d <<= 1) {
        unsigned v = (t >= d) ? part[t - d] : 0u;
        __syncthreads();
        part[t] += v;
        __syncthreads();
    }
    unsigned run = t ? part[t - 1] : 0u;
    for (int i = i0; i < i1; ++i) { unsigned v = cc[i]; cc[i] = run; run += v; }
    __syncthreads();
    for (int j = t; j < NB; j += 256) bstart[s * (NB + 1) + j] = cc[j * WW];
    if (t == 0) bstart[s * (NB + 1) + NB] = Ee;
}

// ---------------- kernel 4: geometry + batch-counting-sort scatter (coalesced record writes)
// record: x = tgt | (src<<15), y = bits(scale)
__global__ __launch_bounds__(256) void scatter_kernel(
    const int4* __restrict__ de4,
    const float4* __restrict__ pn,
    const float2* __restrict__ nwt2,
    const unsigned* __restrict__ cnt,  // per-(s,j,w) exclusive offsets (slice-local)
    uint2* __restrict__ srec) {
    __shared__ uint2 recL[2048];
    __shared__ unsigned short bktL[2048];
    __shared__ unsigned gcur[NB];
    __shared__ unsigned gbA[NB];
    __shared__ unsigned hist[NB + 1];
    __shared__ unsigned bsA[NB + 1];
    __shared__ unsigned scanp[256];
    const int t = threadIdx.x;
    const int s = blockIdx.x & 7;      // slice (XCD-spread)
    const int w = blockIdx.x >> 3;     // 0..31
    const int b = s >> 1, m = s & 1;
    const float4* pnb = pn + b * Nn;
    uint2* srs = srec + (size_t)s * Ee;

    for (int j = t; j < NB; j += 256) gcur[j] = cnt[((size_t)s * NB + j) * WW + w];
    __syncthreads();

    for (int batch = 0; batch < 5; ++batch) {
        const int bb = batch * 2048;
        if (t < NB + 1) hist[t] = 0u;
        __syncthreads();
        uint2 myrec[8];
        int   myj[8];
        #pragma unroll
        for (int k = 0; k < 8; ++k) {
            int el = bb + k * 256 + t;
            int j = NB;
            uint2 rec = make_uint2(0u, 0u);
            if (el < CHK) {
                int4 d4 = de4[(size_t)b * Ee + w * CHK + el];
                float2 nw = nwt2[(size_t)b * Ee + w * CHK + el];
                int tn = m ? d4.y : d4.x;
                int sn = m ? d4.w : d4.z;
                float4 qt = pnb[tn];
                float4 qs = pnb[sn];
                float dx = qt.x - qs.x, dy = qt.y - qs.y;
                float r2 = dx * dx + dy * dy + 1e-6f;
                float sc = (m ? nw.y : nw.x) * (dx * qs.z + dy * qs.w) / r2;
                rec = make_uint2((unsigned)tn | ((unsigned)sn << 15), __float_as_uint(sc));
                j = tn >> 7;
            }
            myrec[k] = rec; myj[k] = j;
            atomicAdd(&hist[j], 1u);
        }
        __syncthreads();
        // block exclusive scan of hist[0..NB]
        unsigned x = (t < NB + 1) ? hist[t] : 0u;
        scanp[t] = x;
        __syncthreads();
        for (int d = 1; d < 256; d <<= 1) {
            unsigned v = (t >= d) ? scanp[t - d] : 0u;
            __syncthreads();
            scanp[t] += v;
            __syncthreads();
        }
        if (t < NB + 1) bsA[t] = scanp[t] - x;
        __syncthreads();
        if (t < NB) { gbA[t] = gcur[t]; gcur[t] += hist[t]; }
        __syncthreads();
        if (t < NB + 1) hist[t] = bsA[t];   // reuse as placement cursor
        __syncthreads();
        #pragma unroll
        for (int k = 0; k < 8; ++k) {
            unsigned slot = atomicAdd(&hist[myj[k]], 1u);
            recL[slot] = myrec[k];
            bktL[slot] = (unsigned short)myj[k];
        }
        __syncthreads();
        const unsigned validN = bsA[NB];
        for (unsigned i = t; i < validN; i += 256) {
            int jj = bktL[i];
            srs[gbA[jj] + (i - bsA[jj])] = recL[i];
        }
        __syncthreads();
    }
}

// ---------------- kernel 5: bucket accumulate, XCD slice-pinned, half-split:
//                  records -> MFMA matvec -> LDS fp32 acc -> pk-fp16 atomic merge
__global__ __launch_bounds__(256, 4) void accum_kernel(
    const float4* __restrict__ pbh4,   // pb fp16 viewed as float4 (4 chunks/row)
    const __half* __restrict__ fTh,
    const uint2* __restrict__ srec,
    const unsigned* __restrict__ bstart,
    const float* __restrict__ wc,
    const float* __restrict__ wsp,
    const float* __restrict__ w0,
    __half* __restrict__ f_out) {      // [b][n][32] fp16 (pre-zeroed)
    __shared__ __align__(16) __half spb[4][16 * 64];   // 8 KB
    __shared__ float acc[QN * 33];                     // 16.9 KB
    const int t  = threadIdx.x;
    const int wv = t >> 6;
    const int l  = t & 63;
    const int c  = l & 15;
    const int q  = l >> 4;
    const int mode = q >> 1;
    const unsigned smask2 = mode ? 0x80008000u : 0u;
    const int s    = blockIdx.x & 7;       // slice = b*2+m (XCD-pinned)
    const int rest = blockIdx.x >> 3;      // 0..313
    const int j    = rest >> 1;            // bucket
    const int h    = rest & 1;             // record-half
    const int b    = s >> 1, m = s & 1;
    const int base = j << 7;
    const int fbase  = b * Nn;
    const int pbbase = s * Nn;

    for (int i = t; i < QN * 33; i += 256) acc[i] = 0.f;
    __syncthreads();

    // loop-invariant B fragments (weights, fp16) for this slice's m
    half8 bf0, bf1;
    #pragma unroll
    for (int jk = 0; jk < 8; ++jk) {
        int k = q * 8 + jk;
        float w0v, w1v;
        if (k < 16) {
            w0v = 2.0f * wc[(c * Kk + k) * Mm + m];
            w1v = 2.0f * wc[((c + 16) * Kk + k) * Mm + m];
        } else {
            w0v = 2.0f * wsp[(c * Kk + (k - 16)) * Mm + m];
            w1v = 2.0f * wsp[((c + 16) * Kk + (k - 16)) * Mm + m];
        }
        bf0[jk] = (_Float16)w0v;
        bf1[jk] = (_Float16)w1v;
    }
    const float acc00 = w0[c * Mm + m] + 1.0f;
    const float acc01 = w0[(c + 16) * Mm + m] + 1.0f;

    __half* myld = spb[wv];
    const int il = l >> 2, jj4 = l & 3;
    float4* wT = (float4*)(myld + il * 64 + 8 * (jj4 ^ (il & 7)));
    float4* wS = (float4*)(myld + il * 64 + 8 * ((4 | jj4) ^ (il & 7)));
    const int cs = c & 7;
    const float4* rBC = (const float4*)(myld + c * 64 + 8 * ((q & 1) ^ cs));
    const float4* rBS = (const float4*)(myld + c * 64 + 8 * ((2 | (q & 1)) ^ cs));
    const float4* rXX = (const float4*)(myld + c * 64 + 8 * ((4 | q) ^ cs));
    const float4* rYY = (const float4*)(myld + c * 64 + 8 * ((4 | (q ^ 2)) ^ cs));

    const unsigned rs = bstart[s * (NB + 1) + j];
    const unsigned re = bstart[s * (NB + 1) + j + 1];
    const int ngroups = (int)((re - rs + 255u) >> 8);
    const int halfg = (ngroups + 1) >> 1;
    const int gs = h ? halfg : 0;
    const int ge = h ? ngroups : halfg;
    if (gs >= ge) return;               // uniform per block

    const u32x2* rb = (const u32x2*)(srec + (size_t)s * Ee);
    const unsigned dummyx = (unsigned)base | ((unsigned)base << 15);
    const u32x2 dummyv = {dummyx, 0u};
    const unsigned rs0 = rs + (unsigned)gs * 256u;
    const int ng = ge - gs;

    unsigned idx0 = rs0 + wv * 64 + l;
    u32x2 rc = (idx0 < re) ? __builtin_nontemporal_load(&rb[idx0]) : dummyv;
    float scf = __uint_as_float(rc.y);
    float4 g0, g2;
    float fa[4], fb[4];
    {   // prologue prefetch for (g=0, tau=0)
        unsigned px = (unsigned)__shfl((int)rc.x, il);
        int tn = px & 32767, sn = (px >> 15) & 32767;
        g0 = pbh4[(size_t)(pbbase + tn) * 4 + jj4];
        g2 = pbh4[(size_t)(pbbase + sn) * 4 + jj4];
        #pragma unroll
        for (int r = 0; r < 4; ++r) {
            unsigned pf = (unsigned)__shfl((int)rc.x, 4 * q + r);
            int sr = (pf >> 15) & 32767;
            fa[r] = __half2float(fTh[(size_t)(fbase + sr) * CIN + c]);
            fb[r] = __half2float(fTh[(size_t)(fbase + sr) * CIN + c + 16]);
        }
    }
    u32x2 rn;
    for (int g = 0; g < ng; ++g) {
        const bool lastg = (g == ng - 1);
        if (!lastg) {
            unsigned idn = rs0 + (unsigned)(g + 1) * 256u + wv * 64 + l;
            rn = (idn < re) ? __builtin_nontemporal_load(&rb[idn]) : dummyv;
        }
        #pragma unroll
        for (int tau = 0; tau < 4; ++tau) {
            // 1. commit prefetched pb rows to LDS (swizzled)
            *wT = g0;
            *wS = g2;
            // 2. A-frag + MFMA (verified R1/R6/R7 math)
            union { float4 v; unsigned u[4]; } ubc, ubs, uxx, uyy;
            ubc.v = *rBC; ubs.v = *rBS; uxx.v = *rXX; uyy.v = *rYY;
            union { half8 h8; unsigned u[4]; } af;
            #pragma unroll
            for (int jp = 0; jp < 4; ++jp) {
                unsigned bsbits = ubs.u[jp] ^ smask2;
                __half2 hb = *(__half2*)&ubc.u[jp];
                __half2 hs = *(__half2*)&bsbits;
                __half2 hx = *(__half2*)&uxx.u[jp];
                __half2 hy = *(__half2*)&uyy.u[jp];
                __half2 v  = __hfma2(hb, hx, __hmul2(hs, hy));
                af.u[jp] = *(unsigned*)&v;
            }
            f32x4 zero = {0.f, 0.f, 0.f, 0.f};
            f32x4 d0 = __builtin_amdgcn_mfma_f32_16x16x32_f16(af.h8, bf0, zero, 0, 0, 0);
            f32x4 d1 = __builtin_amdgcn_mfma_f32_16x16x32_f16(af.h8, bf1, zero, 0, 0, 0);
            // 3. epilogue: ds_add into bucket-local fp32 accumulator
            #pragma unroll
            for (int r = 0; r < 4; ++r) {
                int srcl = tau * 16 + 4 * q + r;
                float sc = __shfl(scf, srcl);
                int tn  = ((unsigned)__shfl((int)rc.x, srcl)) & 32767;
                float v0 = (acc00 + d0[r]) * fa[r] * sc;
                float v1 = (acc01 + d1[r]) * fb[r] * sc;
                int lt = tn - base;
                atomicAdd(&acc[lt * 33 + c], v0);
                atomicAdd(&acc[lt * 33 + c + 16], v1);
            }
            // 4. prefetch next tau (or next group's tau 0)
            if (tau < 3 || !lastg) {
                const int ntau = (tau == 3) ? 0 : tau + 1;
                const unsigned bx = (tau == 3) ? rn.x : rc.x;
                int srcA = ntau * 16 + il;
                unsigned px = (unsigned)__shfl((int)bx, srcA);
                int tn = px & 32767, sn = (px >> 15) & 32767;
                g0 = pbh4[(size_t)(pbbase + tn) * 4 + jj4];
                g2 = pbh4[(size_t)(pbbase + sn) * 4 + jj4];
                #pragma unroll
                for (int r = 0; r < 4; ++r) {
                    unsigned pf = (unsigned)__shfl((int)bx, ntau * 16 + 4 * q + r);
                    int sr = (pf >> 15) & 32767;
                    fa[r] = __half2float(fTh[(size_t)(fbase + sr) * CIN + c]);
                    fb[r] = __half2float(fTh[(size_t)(fbase + sr) * CIN + c + 16]);
                }
            }
        }
        if (!lastg) { rc = rn; scf = __uint_as_float(rc.y); }
    }
    __syncthreads();
    // merge: pk-fp16 atomics, 2 threads/row x 8 pk-ops (contiguous, ~19us total at wall rate)
    {
        int row = t >> 1, h16 = t & 1;
        int n = base + row;
        if (n < Nn) {
            const float* ar = acc + row * 33 + h16 * 16;
            __half* dst = f_out + ((size_t)fbase + n) * CIN + h16 * 16;
            #pragma unroll
            for (int i2 = 0; i2 < 8; ++i2) {
                __half2 hv = __floats2half2_rn(ar[2 * i2], ar[2 * i2 + 1]);
                unsafeAtomicAdd((__half2*)(dst + 2 * i2), hv);
            }
        }
    }
}

// ---------------- kernel 6: out[b,o,n] = bias[o] + sum_i wk[o,i] * f_out[b,n,i]
__global__ __launch_bounds__(256) void out_kernel(
    const float4* __restrict__ f_out4,    // fp16 data viewed as float4 (8 halves)
    const float* __restrict__ wk,
    const float* __restrict__ bias,
    float* __restrict__ out) {
    __shared__ float lwk[1024];
    __shared__ float lf[64 * 33];
    int blk  = blockIdx.x;
    int b    = blk / 313;
    int tile = blk % 313;
    int n0   = tile * 64;
    int t    = threadIdx.x;
    #pragma unroll
    for (int r = 0; r < 4; ++r) lwk[r * 256 + t] = wk[r * 256 + t];
    {
        int nl = t >> 2, i8 = t & 3;
        int n  = n0 + nl;
        union { float4 v; __half2 h[4]; } u;
        u.v = (n < Nn) ? f_out4[((size_t)b * Nn + n) * 4 + i8]
                       : make_float4(0, 0, 0, 0);
        float* p = lf + nl * 33 + i8 * 8;
        #pragma unroll
        for (int j = 0; j < 4; ++j) {
            float2 fj = __half22float2(u.h[j]);
            p[2 * j]     = fj.x;
            p[2 * j + 1] = fj.y;
        }
    }
    __syncthreads();
    int nl = t & 63;
    int og = t >> 6;
    int n  = n0 + nl;
    if (n < Nn) {
        #pragma unroll
        for (int r = 0; r < 8; ++r) {
            int o = r * 4 + og;
            float acc = bias[o];
            #pragma unroll
            for (int i = 0; i < 32; ++i) acc += lwk[o * 32 + i] * lf[nl * 33 + i];
            out[(b * COUT + o) * Nn + n] = acc;
        }
    }
}

extern "C" void kernel_launch(void* const* d_in, const int* in_sizes, int n_in,
                              void* d_out, int out_size, void* d_ws, size_t ws_size,
                              hipStream_t stream) {
    const float* f       = (const float*)d_in[0];
    const float* bases_c = (const float*)d_in[1];
    const float* bases_s = (const float*)d_in[2];
    const float* nodes   = (const float*)d_in[4];
    const float* nrm     = (const float*)d_in[5];
    const int*   de      = (const int*)d_in[6];
    const float* nwt     = (const float*)d_in[7];
    const float* wc      = (const float*)d_in[8];
    const float* wsp     = (const float*)d_in[9];
    const float* w0      = (const float*)d_in[10];
    const float* wk      = (const float*)d_in[11];
    const float* bias    = (const float*)d_in[12];
    float* out = (float*)d_out;

    __half*   fT     = (__half*)d_ws;                          // 5.12 MB
    __half*   pb     = fT + 2560000;                           // 10.24 MB
    float4*   pn     = (float4*)(pb + 5120000);                // 1.28 MB
    __half*   f_out  = (__half*)(pn + 80000);                  // 5.12 MB
    uint2*    srec   = (uint2*)(f_out + 2560000);              // 20.48 MB
    unsigned* cnt    = (unsigned*)(srec + 2560000);            // 160.8 KB
    unsigned* bstart = cnt + 8 * NB * WW;                      // 5.1 KB (ends 42.41 MB)

    prep_fused<<<2500, 256, 0, stream>>>(f, (const float4*)bases_c,
                                         (const float4*)bases_s, nodes, nrm,
                                         fT, (float4*)f_out, pb, pn);
    hist_kernel<<<128, 256, 0, stream>>>((const int2*)de, cnt);
    scan_kernel<<<8, 256, 0, stream>>>(cnt, bstart);
    scatter_kernel<<<256, 256, 0, stream>>>((const int4*)de, pn,
                                            (const float2*)nwt, cnt, srec);
    accum_kernel<<<8 * NB * 2, 256, 0, stream>>>((const float4*)pb, fT, srec, bstart,
                                                 wc, wsp, w0, f_out);
    out_kernel<<<Bb * 313, 256, 0, stream>>>((const float4*)f_out, wk, bias, out);
}